// Round 12
// baseline (394.144 us; speedup 1.0000x reference)
//
#include <hip/hip_runtime.h>
#include <hip/hip_bf16.h>
#include <math.h>

#define MDIM 8192
#define NDIM 4096
#define KDIM 4096
#define WELEMS 16777216
#define XELEMS 33554432

typedef __attribute__((ext_vector_type(8))) short bf16x8;
typedef __attribute__((ext_vector_type(4))) float f32x4;
typedef __attribute__((ext_vector_type(16))) float f32x16;

__device__ __forceinline__ unsigned short f2bf(float f) {
  unsigned int u = __float_as_uint(f);
  u += 0x7fffu + ((u >> 16) & 1u);   // RNE
  return (unsigned short)(u >> 16);
}

__device__ __forceinline__ void gload16(const void* g, void* l) {
  __builtin_amdgcn_global_load_lds(
      (const __attribute__((address_space(1))) void*)g,
      (__attribute__((address_space(3))) void*)l, 16, 0, 0);
}

// ===== numpy-exact fp32 pairwise pieces (verified rounds 3-11) =====
__device__ __forceinline__ float np_tree_reduce(const float* __restrict__ C, float* ls) {
  const int t = threadIdx.x;
  float v[16];
#pragma unroll
  for (int i = 0; i < 16; i++) v[i] = C[t * 16 + i];
#pragma unroll
  for (int n = 16; n > 1; n >>= 1)
    for (int i = 0; i < n / 2; i++) v[i] = v[2 * i] + v[2 * i + 1];
  __syncthreads();
  ls[t] = v[0];
  __syncthreads();
  for (int n = 256; n > 1; n >>= 1) {
    float s = 0.f;
    if (t < n / 2) s = ls[2 * t] + ls[2 * t + 1];
    __syncthreads();
    if (t < n / 2) ls[t] = s;
    __syncthreads();
  }
  float r = ls[0];
  __syncthreads();
  return r;
}

template <int MODE>
__global__ __launch_bounds__(256)
void np_stage1(const float* __restrict__ w, float* __restrict__ C,
               float* __restrict__ C2, const float* __restrict__ scal) {
  __shared__ float ls[32], ls2[32];
  const int t = threadIdx.x;
  const int leaf = t >> 3, j = t & 7;
  const size_t base = (size_t)blockIdx.x * 4096 + leaf * 128 + j;
  float mean = 0.f, lower = 0.f, upper = 0.f;
  if (MODE == 1) mean = scal[0];
  if (MODE == 2) { lower = scal[1]; upper = scal[2]; }
  float r = 0.f, r2 = 0.f;
#pragma unroll
  for (int s = 0; s < 16; s++) {
    float v = w[base + s * 8];
    float tv, tv2 = 0.f;
    if (MODE == 0) tv = v;
    else if (MODE == 1) { float x = v - mean; tv = __fmul_rn(x, x); }
    else {
      bool keep = !(v < lower || v > upper);
      tv = keep ? fabsf(v) : 0.f;
      tv2 = keep ? 1.f : 0.f;
    }
    if (s == 0) { r = tv; r2 = tv2; } else { r += tv; r2 += tv2; }
  }
  r += __shfl_xor(r, 1); r += __shfl_xor(r, 2); r += __shfl_xor(r, 4);
  if (MODE == 2) { r2 += __shfl_xor(r2, 1); r2 += __shfl_xor(r2, 2); r2 += __shfl_xor(r2, 4); }
  if (j == 0) { ls[leaf] = r; if (MODE == 2) ls2[leaf] = r2; }
  __syncthreads();
  if (t == 0) {
    float tmp[32];
    for (int i = 0; i < 32; i++) tmp[i] = ls[i];
    for (int n = 32; n > 1; n >>= 1)
      for (int i = 0; i < n / 2; i++) tmp[i] = tmp[2 * i] + tmp[2 * i + 1];
    C[blockIdx.x] = tmp[0];
    if (MODE == 2) {
      for (int i = 0; i < 32; i++) tmp[i] = ls2[i];
      for (int n = 32; n > 1; n >>= 1)
        for (int i = 0; i < n / 2; i++) tmp[i] = tmp[2 * i] + tmp[2 * i + 1];
      C2[blockIdx.x] = tmp[0];
    }
  }
}

template <int MODE>
__global__ __launch_bounds__(256)
void np_stage2(const float* __restrict__ C, const float* __restrict__ C2,
               float* __restrict__ scal) {
  __shared__ float ls[256], ls2[256];
  const int t = threadIdx.x;
  {
    float v[16];
    for (int i = 0; i < 16; i++) v[i] = C[t * 16 + i];
    for (int n = 16; n > 1; n >>= 1)
      for (int i = 0; i < n / 2; i++) v[i] = v[2 * i] + v[2 * i + 1];
    ls[t] = v[0];
    if (MODE == 2) {
      for (int i = 0; i < 16; i++) v[i] = C2[t * 16 + i];
      for (int n = 16; n > 1; n >>= 1)
        for (int i = 0; i < n / 2; i++) v[i] = v[2 * i] + v[2 * i + 1];
      ls2[t] = v[0];
    }
  }
  __syncthreads();
  if (t == 0) {
    float tmp[256];
    for (int i = 0; i < 256; i++) tmp[i] = ls[i];
    for (int n = 256; n > 1; n >>= 1)
      for (int i = 0; i < n / 2; i++) tmp[i] = tmp[2 * i] + tmp[2 * i + 1];
    float S = tmp[0];
    if (MODE == 0) {
      scal[0] = S / 16777216.0f;
    } else if (MODE == 1) {
      float var = S / 16777215.0f;
      float sd = sqrtf(var);
      float mean = scal[0];
      scal[1] = mean - __fmul_rn(1.96f, sd);
      scal[2] = mean + __fmul_rn(1.96f, sd);
    } else {
      for (int i = 0; i < 256; i++) tmp[i] = ls2[i];
      for (int n = 256; n > 1; n >>= 1)
        for (int i = 0; i < n / 2; i++) tmp[i] = tmp[2 * i] + tmp[2 * i + 1];
      scal[3] = S / tmp[0];
    }
  }
}

// ===== converts =====
__device__ __forceinline__ void pack8(const float* __restrict__ p, unsigned short* dst,
                                      bool dobin, float lower, float upper, float scale) {
  float4 u = *(const float4*)p;
  float4 v = *(const float4*)(p + 4);
  float f[8] = {u.x, u.y, u.z, u.w, v.x, v.y, v.z, v.w};
  unsigned int r[4];
#pragma unroll
  for (int j = 0; j < 4; j++) {
    float a = f[2 * j], b = f[2 * j + 1];
    if (dobin) {
      bool oa = (a < lower) || (a > upper);
      bool ob = (b < lower) || (b > upper);
      a = oa ? a : __fmul_rn(a, scale);
      b = ob ? b : __fmul_rn(b, scale);
    }
    r[j] = (unsigned int)f2bf(a) | ((unsigned int)f2bf(b) << 16);
  }
  *(uint4*)dst = make_uint4(r[0], r[1], r[2], r[3]);
}

__global__ __launch_bounds__(256)
void convert_w(const float* __restrict__ w, unsigned short* __restrict__ wb,
               const float* __restrict__ scal) {
  float lower = scal[1], upper = scal[2], scale = scal[3];
  int tid = blockIdx.x * blockDim.x + threadIdx.x;
  int nth = gridDim.x * blockDim.x;
  int nc = WELEMS / 8;
  for (int i = tid; i < nc; i += nth)
    pack8(w + (size_t)i * 8, wb + (size_t)i * 8, true, lower, upper, scale);
}

// ===== fused prework (verified rounds 9-11) =====
__global__ __launch_bounds__(256)
void k2_var_convx(const float* __restrict__ w, const float* __restrict__ x,
                  const float* __restrict__ C1, float* __restrict__ C2,
                  unsigned short* __restrict__ xb) {
  if (blockIdx.x >= 4096) {
    int bid2 = blockIdx.x - 4096;
    for (int i = bid2 * 256 + threadIdx.x; i < XELEMS / 16; i += 2048 * 256)
      pack8(x + (size_t)i * 8, xb + (size_t)i * 8, false, 0.f, 0.f, 0.f);
    return;
  }
  __shared__ float red[256];
  __shared__ float ls[32];
  float mean = np_tree_reduce(C1, red) / 16777216.0f;
  const int t = threadIdx.x;
  const int leaf = t >> 3, j = t & 7;
  const size_t base = (size_t)blockIdx.x * 4096 + leaf * 128 + j;
  float r = 0.f;
#pragma unroll
  for (int s = 0; s < 16; s++) {
    float v = w[base + s * 8];
    float xv = v - mean;
    float tv = __fmul_rn(xv, xv);
    if (s == 0) r = tv; else r += tv;
  }
  r += __shfl_xor(r, 1); r += __shfl_xor(r, 2); r += __shfl_xor(r, 4);
  if (j == 0) ls[leaf] = r;
  __syncthreads();
  if (t == 0) {
    float tmp[32];
    for (int i = 0; i < 32; i++) tmp[i] = ls[i];
    for (int n = 32; n > 1; n >>= 1)
      for (int i = 0; i < n / 2; i++) tmp[i] = tmp[2 * i] + tmp[2 * i + 1];
    C2[blockIdx.x] = tmp[0];
  }
}

__global__ __launch_bounds__(256)
void k3_keep_convx(const float* __restrict__ w, const float* __restrict__ x,
                   const float* __restrict__ C1, const float* __restrict__ C2,
                   float* __restrict__ C3, float* __restrict__ C4,
                   unsigned short* __restrict__ xb) {
  if (blockIdx.x >= 4096) {
    int bid2 = blockIdx.x - 4096;
    for (int i = XELEMS / 16 + bid2 * 256 + threadIdx.x; i < XELEMS / 8; i += 2048 * 256)
      pack8(x + (size_t)i * 8, xb + (size_t)i * 8, false, 0.f, 0.f, 0.f);
    return;
  }
  __shared__ float red[256];
  __shared__ float ls[32], ls2[32];
  float S1 = np_tree_reduce(C1, red);
  float S2 = np_tree_reduce(C2, red);
  float mean = S1 / 16777216.0f;
  float sd = sqrtf(S2 / 16777215.0f);
  float lower = mean - __fmul_rn(1.96f, sd);
  float upper = mean + __fmul_rn(1.96f, sd);
  const int t = threadIdx.x;
  const int leaf = t >> 3, j = t & 7;
  const size_t base = (size_t)blockIdx.x * 4096 + leaf * 128 + j;
  float r = 0.f, r2 = 0.f;
#pragma unroll
  for (int s = 0; s < 16; s++) {
    float v = w[base + s * 8];
    bool keep = !(v < lower || v > upper);
    float tv = keep ? fabsf(v) : 0.f;
    float tv2 = keep ? 1.f : 0.f;
    if (s == 0) { r = tv; r2 = tv2; } else { r += tv; r2 += tv2; }
  }
  r += __shfl_xor(r, 1); r += __shfl_xor(r, 2); r += __shfl_xor(r, 4);
  r2 += __shfl_xor(r2, 1); r2 += __shfl_xor(r2, 2); r2 += __shfl_xor(r2, 4);
  if (j == 0) { ls[leaf] = r; ls2[leaf] = r2; }
  __syncthreads();
  if (t == 0) {
    float tmp[32];
    for (int i = 0; i < 32; i++) tmp[i] = ls[i];
    for (int n = 32; n > 1; n >>= 1)
      for (int i = 0; i < n / 2; i++) tmp[i] = tmp[2 * i] + tmp[2 * i + 1];
    C3[blockIdx.x] = tmp[0];
    for (int i = 0; i < 32; i++) tmp[i] = ls2[i];
    for (int n = 32; n > 1; n >>= 1)
      for (int i = 0; i < n / 2; i++) tmp[i] = tmp[2 * i] + tmp[2 * i + 1];
    C4[blockIdx.x] = tmp[0];
  }
}

__global__ __launch_bounds__(256)
void k4_convw(const float* __restrict__ w, const float* __restrict__ C1,
              const float* __restrict__ C2, const float* __restrict__ C3,
              const float* __restrict__ C4, unsigned short* __restrict__ wb) {
  __shared__ float red[256];
  float S1 = np_tree_reduce(C1, red);
  float S2 = np_tree_reduce(C2, red);
  float S3 = np_tree_reduce(C3, red);
  float S4 = np_tree_reduce(C4, red);
  float mean = S1 / 16777216.0f;
  float sd = sqrtf(S2 / 16777215.0f);
  float lower = mean - __fmul_rn(1.96f, sd);
  float upper = mean + __fmul_rn(1.96f, sd);
  float scale = S3 / S4;
  int tid = blockIdx.x * blockDim.x + threadIdx.x;
  int nth = gridDim.x * blockDim.x;
  int nc = WELEMS / 8;
  for (int i = tid; i < nc; i += nth)
    pack8(w + (size_t)i * 8, wb + (size_t)i * 8, true, lower, upper, scale);
}

// ===== 256x256 GEMM: r6 schedule (BK=64, 2-dbuf, 2-barrier phases, VM6
// stagger — verified 284us bit-exact) converted to 32x32x16 MFMA =====
// Rationale: 32x32x16 ubench 2382 TF vs 16x16x32's 2075 (+15% pipe rate),
// half the issue slots for same FLOPs. LDS layout/staging byte-identical;
// 32x32 reads stay conflict-free: lane reads row l&31, granule g=s*2+(l>>5)
// at position g^(row&7) -> per-16-lane banks 4*(g^(r&7)) = 8 distinct x
// 2-way (free, m136). C/D layout: col=lane&31, row=(q&3)+8*(q>>2)+4*(l>>5).

#define VM(n) asm volatile("s_waitcnt vmcnt(" #n ")" ::: "memory")
#define LGK8 asm volatile("s_waitcnt lgkmcnt(8)" ::: "memory")
#define PSYNC { asm volatile("" ::: "memory"); __builtin_amdgcn_s_barrier(); asm volatile("" ::: "memory"); }

// load A-half mh (2 m-tiles x 4 k-slices) into a[2][4]
#define RDA(buf, mh) do { \
  a[0][0] = *(const bf16x8*)&sA[buf][wm][((mh)*64 +  0 + l31)*64 + koo0]; \
  a[0][1] = *(const bf16x8*)&sA[buf][wm][((mh)*64 +  0 + l31)*64 + koo1]; \
  a[0][2] = *(const bf16x8*)&sA[buf][wm][((mh)*64 +  0 + l31)*64 + koo2]; \
  a[0][3] = *(const bf16x8*)&sA[buf][wm][((mh)*64 +  0 + l31)*64 + koo3]; \
  a[1][0] = *(const bf16x8*)&sA[buf][wm][((mh)*64 + 32 + l31)*64 + koo0]; \
  a[1][1] = *(const bf16x8*)&sA[buf][wm][((mh)*64 + 32 + l31)*64 + koo1]; \
  a[1][2] = *(const bf16x8*)&sA[buf][wm][((mh)*64 + 32 + l31)*64 + koo2]; \
  a[1][3] = *(const bf16x8*)&sA[buf][wm][((mh)*64 + 32 + l31)*64 + koo3]; } while (0)

// load B n-tile nh (4 k-slices) into slot[4]
#define RDB(slot, buf, nh) do { \
  slot[0] = *(const bf16x8*)&sB[buf][wnh][(wnq*64 + (nh)*32 + l31)*64 + koo0]; \
  slot[1] = *(const bf16x8*)&sB[buf][wnh][(wnq*64 + (nh)*32 + l31)*64 + koo1]; \
  slot[2] = *(const bf16x8*)&sB[buf][wnh][(wnq*64 + (nh)*32 + l31)*64 + koo2]; \
  slot[3] = *(const bf16x8*)&sB[buf][wnh][(wnq*64 + (nh)*32 + l31)*64 + koo3]; } while (0)

// quadrant (mh, nh): 8 x mfma_32x32x16, k ascending per acc
#define MM(mh, nh, BS) do { \
  __builtin_amdgcn_s_setprio(1); \
  acc[(mh)*2+0][nh] = __builtin_amdgcn_mfma_f32_32x32x16_bf16(a[0][0], BS[0], acc[(mh)*2+0][nh], 0, 0, 0); \
  acc[(mh)*2+1][nh] = __builtin_amdgcn_mfma_f32_32x32x16_bf16(a[1][0], BS[0], acc[(mh)*2+1][nh], 0, 0, 0); \
  acc[(mh)*2+0][nh] = __builtin_amdgcn_mfma_f32_32x32x16_bf16(a[0][1], BS[1], acc[(mh)*2+0][nh], 0, 0, 0); \
  acc[(mh)*2+1][nh] = __builtin_amdgcn_mfma_f32_32x32x16_bf16(a[1][1], BS[1], acc[(mh)*2+1][nh], 0, 0, 0); \
  acc[(mh)*2+0][nh] = __builtin_amdgcn_mfma_f32_32x32x16_bf16(a[0][2], BS[2], acc[(mh)*2+0][nh], 0, 0, 0); \
  acc[(mh)*2+1][nh] = __builtin_amdgcn_mfma_f32_32x32x16_bf16(a[1][2], BS[2], acc[(mh)*2+1][nh], 0, 0, 0); \
  acc[(mh)*2+0][nh] = __builtin_amdgcn_mfma_f32_32x32x16_bf16(a[0][3], BS[3], acc[(mh)*2+0][nh], 0, 0, 0); \
  acc[(mh)*2+1][nh] = __builtin_amdgcn_mfma_f32_32x32x16_bf16(a[1][3], BS[3], acc[(mh)*2+1][nh], 0, 0, 0); \
  __builtin_amdgcn_s_setprio(0); } while (0)

#define STGA(buf, q, kadd) do { \
  gload16(xbp + aofA[0][q] + (kadd), &sA[buf][0][(q)*4096 + t8]); \
  gload16(xbp + aofA[1][q] + (kadd), &sA[buf][1][(q)*4096 + t8]); } while (0)
#define STGB(buf, h, kadd) do { \
  gload16(wbp + bofB[h][0] + (kadd), &sB[buf][h][t8]); \
  gload16(wbp + bofB[h][1] + (kadd), &sB[buf][h][4096 + t8]); } while (0)

__global__ __launch_bounds__(512, 2)
void gemm256(const unsigned short* __restrict__ xbp, const unsigned short* __restrict__ wbp,
             const float* __restrict__ bias, float* __restrict__ out) {
  __shared__ unsigned short sA[2][2][8192];
  __shared__ unsigned short sB[2][2][8192];

  // XCD-aware bijective swizzle: grid 512 = 32(M) x 16(N)
  const int bid = blockIdx.x;
  const int swz = (bid & 7) * 64 + (bid >> 3);
  const int bm = swz >> 4, bn = swz & 15;

  const int t = threadIdx.x;
  const int lane = t & 63;
  const int wid = t >> 6;
  const int wm = wid >> 2, wn = wid & 3;
  const int wnh = wn >> 1, wnq = wn & 1;
  const int l31 = lane & 31;
  const int l7 = lane & 7;
  const int kh2 = lane >> 5;
  // granule g = s*2 + kh2 stored at position g ^ (row&7); row&7 == l7
  const int koo0 = 8 * ((0 + kh2) ^ l7);
  const int koo1 = 8 * ((2 + kh2) ^ l7);
  const int koo2 = 8 * ((4 + kh2) ^ l7);
  const int koo3 = 8 * ((6 + kh2) ^ l7);

  const int t8 = t * 8;
  const int rl = t >> 3;
  const int cs = ((t & 7) * 8) ^ ((rl & 7) << 3);   // inverse-swizzled src col
  unsigned int aofA[2][2], bofB[2][2];
#pragma unroll
  for (int h = 0; h < 2; h++)
#pragma unroll
    for (int q = 0; q < 2; q++) {
      aofA[h][q] = (unsigned int)((bm * 256 + h * 128 + q * 64 + rl) * KDIM + cs);
      bofB[h][q] = (unsigned int)((bn * 256 + h * 128 + q * 64 + rl) * KDIM + cs);
    }

  f32x16 acc[4][2];
#pragma unroll
  for (int i = 0; i < 4; i++)
#pragma unroll
    for (int j = 0; j < 2; j++)
#pragma unroll
      for (int q = 0; q < 16; q++) acc[i][j][q] = 0.f;

  bf16x8 a[2][4], b0[4], b1[4];

  // prologue: T0 full (8 loads) + T1 B0,B1,A0 (6) = 14 outstanding
  STGA(0, 0, 0); STGB(0, 0, 0); STGB(0, 1, 0); STGA(0, 1, 0);
  STGB(1, 0, 64); STGB(1, 1, 64); STGA(1, 0, 64);
  VM(6); PSYNC;                    // confirm T0's 8; invariant: 6 outstanding

  const int NIT = KDIM / 128;      // 32 iterations, 2 K-tiles each
  for (int it = 0; it < NIT; ++it) {
    const bool last = (it == NIT - 1);
    const int kuB = it * 128 + 64;   // T1 (buf1) K offset
    const int kuN = kuB + 64;        // T0' (buf0 next)
    const int kuL = kuB + 128;       // T1' (buf1 next)

    // ---- tile T0 (buf0): quadrants (0,0),(0,1),(1,1),(1,0) ----
    RDA(0, 0); RDB(b0, 0, 0);
    STGA(1, 1, kuB);                 // T1.A1 (dead since prev ph7)
    LGK8; PSYNC;
    MM(0, 0, b0); PSYNC;

    RDB(b1, 0, 1);
    PSYNC;
    MM(0, 1, b1); PSYNC;

    RDA(0, 1);
    if (!last) { STGB(0, 0, kuN); STGB(0, 1, kuN); }  // T0'.B (dead since ph2)
    PSYNC;
    MM(1, 1, b1); PSYNC;

    if (!last) STGA(0, 0, kuN);      // T0'.A0 (dead since ph1)
    if (last) { VM(0); } else { VM(6); } // confirm T1 (8 oldest of 14)
    PSYNC;
    MM(1, 0, b0); PSYNC;

    // ---- tile T1 (buf1) ----
    RDA(1, 0); RDB(b0, 1, 0);
    if (!last) STGA(0, 1, kuN);      // T0'.A1 (dead since ph3)
    LGK8; PSYNC;
    MM(0, 0, b0); PSYNC;

    RDB(b1, 1, 1);
    PSYNC;
    MM(0, 1, b1); PSYNC;

    RDA(1, 1);
    if (!last) { STGB(1, 0, kuL); STGB(1, 1, kuL); }  // T1'.B (dead since ph6)
    PSYNC;
    MM(1, 1, b1); PSYNC;

    if (!last) { STGA(1, 0, kuL); VM(6); }  // T1'.A0; confirm T0'
    PSYNC;
    MM(1, 0, b0); PSYNC;
  }

  // epilogue: 32x32 C/D layout col=lane&31, row=(q&3)+8*(q>>2)+4*(lane>>5)
  const int rquad = kh2 * 4;
#pragma unroll
  for (int nh = 0; nh < 2; ++nh) {
    const int col = bn * 256 + wn * 64 + nh * 32 + l31;
    const float bv = bias[col];
#pragma unroll
    for (int mi = 0; mi < 4; ++mi) {
      const int row0 = bm * 256 + wm * 128 + mi * 32 + rquad;
#pragma unroll
      for (int q = 0; q < 16; ++q) {
        const int row = row0 + (q & 3) + 8 * (q >> 2);
        out[(size_t)row * NDIM + col] = acc[mi][nh][q] + bv;
      }
    }
  }
}

// ===== fallback 128^2 GEMM (round-3 verified) for small-ws paths =====
template <bool A_BF16, bool B_BF16>
__global__ __launch_bounds__(256)
void gemm_bt(const void* __restrict__ Av, const void* __restrict__ Bv,
             const float* __restrict__ bias, float* __restrict__ out,
             const float* __restrict__ scal) {
  __shared__ unsigned short sAt[2][128 * 32];
  __shared__ unsigned short sBt[2][128 * 32];
  float lower = 0.f, upper = 0.f, scale = 0.f;
  if constexpr (!B_BF16) { lower = scal[1]; upper = scal[2]; scale = scal[3]; }
  const unsigned short* Ab = (const unsigned short*)Av;
  const float* Af = (const float*)Av;
  const unsigned short* Bb = (const unsigned short*)Bv;
  const float* Bf = (const float*)Bv;
  int bid = blockIdx.x;
  int swz = (bid & 7) * 256 + (bid >> 3);
  int bm = swz >> 5, bn = swz & 31;
  const int t = threadIdx.x, lane = t & 63, wid = t >> 6;
  const int wm = wid >> 1, wn = wid & 1;
  const int e0 = t * 8, e1 = e0 + 2048;
  const size_t aOff0 = (size_t)(bm * 128 + (e0 >> 5)) * KDIM + (e0 & 31);
  const size_t aOff1 = (size_t)(bm * 128 + (e1 >> 5)) * KDIM + (e1 & 31);
  const size_t bOff0 = (size_t)(bn * 128 + (e0 >> 5)) * KDIM + (e0 & 31);
  const size_t bOff1 = (size_t)(bn * 128 + (e1 >> 5)) * KDIM + (e1 & 31);
  f32x4 acc[4][4];
#pragma unroll
  for (int i = 0; i < 4; i++)
#pragma unroll
    for (int j = 0; j < 4; j++) acc[i][j] = {0.f, 0.f, 0.f, 0.f};
  auto stage = [&](int buf, int k0) {
    if constexpr (A_BF16) {
      gload16(Ab + aOff0 + k0, &sAt[buf][e0]);
      gload16(Ab + aOff1 + k0, &sAt[buf][e1]);
    } else {
      pack8(Af + aOff0 + k0, &sAt[buf][e0], false, 0.f, 0.f, 0.f);
      pack8(Af + aOff1 + k0, &sAt[buf][e1], false, 0.f, 0.f, 0.f);
    }
    if constexpr (B_BF16) {
      gload16(Bb + bOff0 + k0, &sBt[buf][e0]);
      gload16(Bb + bOff1 + k0, &sBt[buf][e1]);
    } else {
      pack8(Bf + bOff0 + k0, &sBt[buf][e0], true, lower, upper, scale);
      pack8(Bf + bOff1 + k0, &sBt[buf][e1], true, lower, upper, scale);
    }
  };
  stage(0, 0);
  const int NT = KDIM / 32;
  const int ko = (lane >> 4) * 8, fr = lane & 15;
  for (int tt = 0; tt < NT; ++tt) {
    int cur = tt & 1;
    __syncthreads();
    if (tt + 1 < NT) stage(cur ^ 1, (tt + 1) * 32);
    bf16x8 a[4], b[4];
#pragma unroll
    for (int i = 0; i < 4; i++) {
      a[i] = *(const bf16x8*)&sAt[cur][(wm * 64 + i * 16 + fr) * 32 + ko];
      b[i] = *(const bf16x8*)&sBt[cur][(wn * 64 + i * 16 + fr) * 32 + ko];
    }
#pragma unroll
    for (int i = 0; i < 4; i++)
#pragma unroll
      for (int j = 0; j < 4; j++)
        acc[i][j] = __builtin_amdgcn_mfma_f32_16x16x32_bf16(a[i], b[j], acc[i][j], 0, 0, 0);
  }
  const int colbase = bn * 128 + wn * 64 + (lane & 15);
  const int rowbase = bm * 128 + wm * 64 + (lane >> 4) * 4;
#pragma unroll
  for (int j = 0; j < 4; j++) {
    int col = colbase + j * 16;
    float bv = bias[col];
#pragma unroll
    for (int i = 0; i < 4; i++) {
      int row0 = rowbase + i * 16;
#pragma unroll
      for (int q = 0; q < 4; q++)
        out[(size_t)(row0 + q) * NDIM + col] = acc[i][j][q] + bv;
    }
  }
}

extern "C" void kernel_launch(void* const* d_in, const int* in_sizes, int n_in,
                              void* d_out, int out_size, void* d_ws, size_t ws_size,
                              hipStream_t stream) {
  const float* x = (const float*)d_in[0];
  const float* w = (const float*)d_in[1];
  const float* bias = (const float*)d_in[2];
  float* out = (float*)d_out;
  char* ws = (char*)d_ws;

  const size_t xb_b = (size_t)XELEMS * 2;   // 64 MB
  const size_t wb_b = (size_t)WELEMS * 2;   // 32 MB
  const size_t c_b = 4 * 4096 * sizeof(float);
  const bool full = ws_size >= xb_b + wb_b + c_b + 64;
  const bool wonly = !full && ws_size >= wb_b + c_b + 64;

  unsigned short *xb = nullptr, *wb = nullptr;
  float *C1, *scal;
  if (full) {
    xb = (unsigned short*)ws;
    wb = (unsigned short*)(ws + xb_b);
    C1 = (float*)(ws + xb_b + wb_b);
  } else if (wonly) {
    wb = (unsigned short*)ws;
    C1 = (float*)(ws + wb_b);
  } else {
    C1 = (float*)ws;
  }
  float* C2 = C1 + 4096;
  float* C3 = C2 + 4096;
  float* C4 = C3 + 4096;
  scal = C4 + 4096;

  if (full) {
    np_stage1<0><<<dim3(4096), dim3(256), 0, stream>>>(w, C1, nullptr, scal);
    k2_var_convx<<<dim3(6144), dim3(256), 0, stream>>>(w, x, C1, C2, xb);
    k3_keep_convx<<<dim3(6144), dim3(256), 0, stream>>>(w, x, C1, C2, C3, C4, xb);
    k4_convw<<<dim3(2048), dim3(256), 0, stream>>>(w, C1, C2, C3, C4, wb);
    gemm256<<<dim3(512), dim3(512), 0, stream>>>(xb, wb, bias, out);
  } else {
    np_stage1<0><<<dim3(4096), dim3(256), 0, stream>>>(w, C1, nullptr, scal);
    np_stage2<0><<<dim3(1), dim3(256), 0, stream>>>(C1, nullptr, scal);
    np_stage1<1><<<dim3(4096), dim3(256), 0, stream>>>(w, C2, nullptr, scal);
    np_stage2<1><<<dim3(1), dim3(256), 0, stream>>>(C2, nullptr, scal);
    np_stage1<2><<<dim3(4096), dim3(256), 0, stream>>>(w, C3, C4, scal);
    np_stage2<2><<<dim3(1), dim3(256), 0, stream>>>(C3, C4, scal);
    if (wonly) {
      convert_w<<<dim3(2048), dim3(256), 0, stream>>>(w, wb, scal);
      gemm_bt<false, true><<<dim3(2048), dim3(256), 0, stream>>>(x, wb, bias, out, scal);
    } else {
      gemm_bt<false, false><<<dim3(2048), dim3(256), 0, stream>>>(x, w, bias, out, scal);
    }
  }
}

// Round 13
// 376.320 us; speedup vs baseline: 1.0474x; 1.0474x over previous
//
#include <hip/hip_runtime.h>
#include <hip/hip_bf16.h>
#include <math.h>

#define MDIM 8192
#define NDIM 4096
#define KDIM 4096
#define WELEMS 16777216
#define XELEMS 33554432

typedef __attribute__((ext_vector_type(8))) short bf16x8;
typedef __attribute__((ext_vector_type(4))) float f32x4;

__device__ __forceinline__ unsigned short f2bf(float f) {
  unsigned int u = __float_as_uint(f);
  u += 0x7fffu + ((u >> 16) & 1u);   // RNE
  return (unsigned short)(u >> 16);
}

__device__ __forceinline__ void gload16(const void* g, void* l) {
  __builtin_amdgcn_global_load_lds(
      (const __attribute__((address_space(1))) void*)g,
      (__attribute__((address_space(3))) void*)l, 16, 0, 0);
}

// ===== numpy-exact fp32 pairwise pieces (verified rounds 3-11) =====
__device__ __forceinline__ float np_tree_reduce(const float* __restrict__ C, float* ls) {
  const int t = threadIdx.x;
  float v[16];
#pragma unroll
  for (int i = 0; i < 16; i++) v[i] = C[t * 16 + i];
#pragma unroll
  for (int n = 16; n > 1; n >>= 1)
    for (int i = 0; i < n / 2; i++) v[i] = v[2 * i] + v[2 * i + 1];
  __syncthreads();
  ls[t] = v[0];
  __syncthreads();
  for (int n = 256; n > 1; n >>= 1) {
    float s = 0.f;
    if (t < n / 2) s = ls[2 * t] + ls[2 * t + 1];
    __syncthreads();
    if (t < n / 2) ls[t] = s;
    __syncthreads();
  }
  float r = ls[0];
  __syncthreads();
  return r;
}

template <int MODE>
__global__ __launch_bounds__(256)
void np_stage1(const float* __restrict__ w, float* __restrict__ C,
               float* __restrict__ C2, const float* __restrict__ scal) {
  __shared__ float ls[32], ls2[32];
  const int t = threadIdx.x;
  const int leaf = t >> 3, j = t & 7;
  const size_t base = (size_t)blockIdx.x * 4096 + leaf * 128 + j;
  float mean = 0.f, lower = 0.f, upper = 0.f;
  if (MODE == 1) mean = scal[0];
  if (MODE == 2) { lower = scal[1]; upper = scal[2]; }
  float r = 0.f, r2 = 0.f;
#pragma unroll
  for (int s = 0; s < 16; s++) {
    float v = w[base + s * 8];
    float tv, tv2 = 0.f;
    if (MODE == 0) tv = v;
    else if (MODE == 1) { float x = v - mean; tv = __fmul_rn(x, x); }
    else {
      bool keep = !(v < lower || v > upper);
      tv = keep ? fabsf(v) : 0.f;
      tv2 = keep ? 1.f : 0.f;
    }
    if (s == 0) { r = tv; r2 = tv2; } else { r += tv; r2 += tv2; }
  }
  r += __shfl_xor(r, 1); r += __shfl_xor(r, 2); r += __shfl_xor(r, 4);
  if (MODE == 2) { r2 += __shfl_xor(r2, 1); r2 += __shfl_xor(r2, 2); r2 += __shfl_xor(r2, 4); }
  if (j == 0) { ls[leaf] = r; if (MODE == 2) ls2[leaf] = r2; }
  __syncthreads();
  if (t == 0) {
    float tmp[32];
    for (int i = 0; i < 32; i++) tmp[i] = ls[i];
    for (int n = 32; n > 1; n >>= 1)
      for (int i = 0; i < n / 2; i++) tmp[i] = tmp[2 * i] + tmp[2 * i + 1];
    C[blockIdx.x] = tmp[0];
    if (MODE == 2) {
      for (int i = 0; i < 32; i++) tmp[i] = ls2[i];
      for (int n = 32; n > 1; n >>= 1)
        for (int i = 0; i < n / 2; i++) tmp[i] = tmp[2 * i] + tmp[2 * i + 1];
      C2[blockIdx.x] = tmp[0];
    }
  }
}

template <int MODE>
__global__ __launch_bounds__(256)
void np_stage2(const float* __restrict__ C, const float* __restrict__ C2,
               float* __restrict__ scal) {
  __shared__ float ls[256], ls2[256];
  const int t = threadIdx.x;
  {
    float v[16];
    for (int i = 0; i < 16; i++) v[i] = C[t * 16 + i];
    for (int n = 16; n > 1; n >>= 1)
      for (int i = 0; i < n / 2; i++) v[i] = v[2 * i] + v[2 * i + 1];
    ls[t] = v[0];
    if (MODE == 2) {
      for (int i = 0; i < 16; i++) v[i] = C2[t * 16 + i];
      for (int n = 16; n > 1; n >>= 1)
        for (int i = 0; i < n / 2; i++) v[i] = v[2 * i] + v[2 * i + 1];
      ls2[t] = v[0];
    }
  }
  __syncthreads();
  if (t == 0) {
    float tmp[256];
    for (int i = 0; i < 256; i++) tmp[i] = ls[i];
    for (int n = 256; n > 1; n >>= 1)
      for (int i = 0; i < n / 2; i++) tmp[i] = tmp[2 * i] + tmp[2 * i + 1];
    float S = tmp[0];
    if (MODE == 0) {
      scal[0] = S / 16777216.0f;
    } else if (MODE == 1) {
      float var = S / 16777215.0f;
      float sd = sqrtf(var);
      float mean = scal[0];
      scal[1] = mean - __fmul_rn(1.96f, sd);
      scal[2] = mean + __fmul_rn(1.96f, sd);
    } else {
      for (int i = 0; i < 256; i++) tmp[i] = ls2[i];
      for (int n = 256; n > 1; n >>= 1)
        for (int i = 0; i < n / 2; i++) tmp[i] = tmp[2 * i] + tmp[2 * i + 1];
      scal[3] = S / tmp[0];
    }
  }
}

// ===== converts =====
__device__ __forceinline__ void pack8(const float* __restrict__ p, unsigned short* dst,
                                      bool dobin, float lower, float upper, float scale) {
  float4 u = *(const float4*)p;
  float4 v = *(const float4*)(p + 4);
  float f[8] = {u.x, u.y, u.z, u.w, v.x, v.y, v.z, v.w};
  unsigned int r[4];
#pragma unroll
  for (int j = 0; j < 4; j++) {
    float a = f[2 * j], b = f[2 * j + 1];
    if (dobin) {
      bool oa = (a < lower) || (a > upper);
      bool ob = (b < lower) || (b > upper);
      a = oa ? a : __fmul_rn(a, scale);
      b = ob ? b : __fmul_rn(b, scale);
    }
    r[j] = (unsigned int)f2bf(a) | ((unsigned int)f2bf(b) << 16);
  }
  *(uint4*)dst = make_uint4(r[0], r[1], r[2], r[3]);
}

__global__ __launch_bounds__(256)
void convert_w(const float* __restrict__ w, unsigned short* __restrict__ wb,
               const float* __restrict__ scal) {
  float lower = scal[1], upper = scal[2], scale = scal[3];
  int tid = blockIdx.x * blockDim.x + threadIdx.x;
  int nth = gridDim.x * blockDim.x;
  int nc = WELEMS / 8;
  for (int i = tid; i < nc; i += nth)
    pack8(w + (size_t)i * 8, wb + (size_t)i * 8, true, lower, upper, scale);
}

// ===== fused prework (verified rounds 9-11) =====
__global__ __launch_bounds__(256)
void k2_var_convx(const float* __restrict__ w, const float* __restrict__ x,
                  const float* __restrict__ C1, float* __restrict__ C2,
                  unsigned short* __restrict__ xb) {
  if (blockIdx.x >= 4096) {
    int bid2 = blockIdx.x - 4096;
    for (int i = bid2 * 256 + threadIdx.x; i < XELEMS / 16; i += 2048 * 256)
      pack8(x + (size_t)i * 8, xb + (size_t)i * 8, false, 0.f, 0.f, 0.f);
    return;
  }
  __shared__ float red[256];
  __shared__ float ls[32];
  float mean = np_tree_reduce(C1, red) / 16777216.0f;
  const int t = threadIdx.x;
  const int leaf = t >> 3, j = t & 7;
  const size_t base = (size_t)blockIdx.x * 4096 + leaf * 128 + j;
  float r = 0.f;
#pragma unroll
  for (int s = 0; s < 16; s++) {
    float v = w[base + s * 8];
    float xv = v - mean;
    float tv = __fmul_rn(xv, xv);
    if (s == 0) r = tv; else r += tv;
  }
  r += __shfl_xor(r, 1); r += __shfl_xor(r, 2); r += __shfl_xor(r, 4);
  if (j == 0) ls[leaf] = r;
  __syncthreads();
  if (t == 0) {
    float tmp[32];
    for (int i = 0; i < 32; i++) tmp[i] = ls[i];
    for (int n = 32; n > 1; n >>= 1)
      for (int i = 0; i < n / 2; i++) tmp[i] = tmp[2 * i] + tmp[2 * i + 1];
    C2[blockIdx.x] = tmp[0];
  }
}

__global__ __launch_bounds__(256)
void k3_keep_convx(const float* __restrict__ w, const float* __restrict__ x,
                   const float* __restrict__ C1, const float* __restrict__ C2,
                   float* __restrict__ C3, float* __restrict__ C4,
                   unsigned short* __restrict__ xb) {
  if (blockIdx.x >= 4096) {
    int bid2 = blockIdx.x - 4096;
    for (int i = XELEMS / 16 + bid2 * 256 + threadIdx.x; i < XELEMS / 8; i += 2048 * 256)
      pack8(x + (size_t)i * 8, xb + (size_t)i * 8, false, 0.f, 0.f, 0.f);
    return;
  }
  __shared__ float red[256];
  __shared__ float ls[32], ls2[32];
  float S1 = np_tree_reduce(C1, red);
  float S2 = np_tree_reduce(C2, red);
  float mean = S1 / 16777216.0f;
  float sd = sqrtf(S2 / 16777215.0f);
  float lower = mean - __fmul_rn(1.96f, sd);
  float upper = mean + __fmul_rn(1.96f, sd);
  const int t = threadIdx.x;
  const int leaf = t >> 3, j = t & 7;
  const size_t base = (size_t)blockIdx.x * 4096 + leaf * 128 + j;
  float r = 0.f, r2 = 0.f;
#pragma unroll
  for (int s = 0; s < 16; s++) {
    float v = w[base + s * 8];
    bool keep = !(v < lower || v > upper);
    float tv = keep ? fabsf(v) : 0.f;
    float tv2 = keep ? 1.f : 0.f;
    if (s == 0) { r = tv; r2 = tv2; } else { r += tv; r2 += tv2; }
  }
  r += __shfl_xor(r, 1); r += __shfl_xor(r, 2); r += __shfl_xor(r, 4);
  r2 += __shfl_xor(r2, 1); r2 += __shfl_xor(r2, 2); r2 += __shfl_xor(r2, 4);
  if (j == 0) { ls[leaf] = r; ls2[leaf] = r2; }
  __syncthreads();
  if (t == 0) {
    float tmp[32];
    for (int i = 0; i < 32; i++) tmp[i] = ls[i];
    for (int n = 32; n > 1; n >>= 1)
      for (int i = 0; i < n / 2; i++) tmp[i] = tmp[2 * i] + tmp[2 * i + 1];
    C3[blockIdx.x] = tmp[0];
    for (int i = 0; i < 32; i++) tmp[i] = ls2[i];
    for (int n = 32; n > 1; n >>= 1)
      for (int i = 0; i < n / 2; i++) tmp[i] = tmp[2 * i] + tmp[2 * i + 1];
    C4[blockIdx.x] = tmp[0];
  }
}

__global__ __launch_bounds__(256)
void k4_convw(const float* __restrict__ w, const float* __restrict__ C1,
              const float* __restrict__ C2, const float* __restrict__ C3,
              const float* __restrict__ C4, unsigned short* __restrict__ wb) {
  __shared__ float red[256];
  float S1 = np_tree_reduce(C1, red);
  float S2 = np_tree_reduce(C2, red);
  float S3 = np_tree_reduce(C3, red);
  float S4 = np_tree_reduce(C4, red);
  float mean = S1 / 16777216.0f;
  float sd = sqrtf(S2 / 16777215.0f);
  float lower = mean - __fmul_rn(1.96f, sd);
  float upper = mean + __fmul_rn(1.96f, sd);
  float scale = S3 / S4;
  int tid = blockIdx.x * blockDim.x + threadIdx.x;
  int nth = gridDim.x * blockDim.x;
  int nc = WELEMS / 8;
  for (int i = tid; i < nc; i += nth)
    pack8(w + (size_t)i * 8, wb + (size_t)i * 8, true, lower, upper, scale);
}

// ===== 256x256 GEMM: BK=32, 4-deep LDS ring, 4 phases/K-tile (r11, 267us) =====
// 8 waves 2Mx4N; LDS 128KB = 4 bufs x (A 128rowsx2 + B) x 32k. Per K-tile:
// 12 ds_read_b128, 4 gload_lds, 32 MFMA (4 phases x 8, one k-slice each),
// ONE VM(6) per tile confirming loads issued 3 K-tiles (~10 phases) earlier;
// steady 10 wave-loads in flight (80KB/block MLP). Block-swizzle sigma(r)=
// (r>>1)&3 on 8-elem groups: 2-way banks (free), lane-invariant read offset.
// Accumulation order (k ascending, one mfma/tile/acc) identical to r8/r10.

#define VM(n) asm volatile("s_waitcnt vmcnt(" #n ")" ::: "memory")
#define PSYNC { asm volatile("" ::: "memory"); __builtin_amdgcn_s_barrier(); asm volatile("" ::: "memory"); }

#define RDA4(slot, buf, h) do { \
  slot[0] = *(const bf16x8*)&sA[buf][wm][((h)*64 +  0 + fr)*32 + koo]; \
  slot[1] = *(const bf16x8*)&sA[buf][wm][((h)*64 + 16 + fr)*32 + koo]; \
  slot[2] = *(const bf16x8*)&sA[buf][wm][((h)*64 + 32 + fr)*32 + koo]; \
  slot[3] = *(const bf16x8*)&sA[buf][wm][((h)*64 + 48 + fr)*32 + koo]; } while (0)

#define RDB2(slot, buf, bh) do { \
  slot[0] = *(const bf16x8*)&sB[buf][wnh][(wnq*64 + ((bh)*2+0)*16 + fr)*32 + koo]; \
  slot[1] = *(const bf16x8*)&sB[buf][wnh][(wnq*64 + ((bh)*2+1)*16 + fr)*32 + koo]; } while (0)

#define MMH(AS, BS, mh, n2) do { \
  __builtin_amdgcn_s_setprio(1); \
  acc[(mh)*4+0][(n2)*2+0] = __builtin_amdgcn_mfma_f32_16x16x32_bf16(AS[0], BS[0], acc[(mh)*4+0][(n2)*2+0], 0, 0, 0); \
  acc[(mh)*4+0][(n2)*2+1] = __builtin_amdgcn_mfma_f32_16x16x32_bf16(AS[0], BS[1], acc[(mh)*4+0][(n2)*2+1], 0, 0, 0); \
  acc[(mh)*4+1][(n2)*2+0] = __builtin_amdgcn_mfma_f32_16x16x32_bf16(AS[1], BS[0], acc[(mh)*4+1][(n2)*2+0], 0, 0, 0); \
  acc[(mh)*4+1][(n2)*2+1] = __builtin_amdgcn_mfma_f32_16x16x32_bf16(AS[1], BS[1], acc[(mh)*4+1][(n2)*2+1], 0, 0, 0); \
  acc[(mh)*4+2][(n2)*2+0] = __builtin_amdgcn_mfma_f32_16x16x32_bf16(AS[2], BS[0], acc[(mh)*4+2][(n2)*2+0], 0, 0, 0); \
  acc[(mh)*4+2][(n2)*2+1] = __builtin_amdgcn_mfma_f32_16x16x32_bf16(AS[2], BS[1], acc[(mh)*4+2][(n2)*2+1], 0, 0, 0); \
  acc[(mh)*4+3][(n2)*2+0] = __builtin_amdgcn_mfma_f32_16x16x32_bf16(AS[3], BS[0], acc[(mh)*4+3][(n2)*2+0], 0, 0, 0); \
  acc[(mh)*4+3][(n2)*2+1] = __builtin_amdgcn_mfma_f32_16x16x32_bf16(AS[3], BS[1], acc[(mh)*4+3][(n2)*2+1], 0, 0, 0); \
  __builtin_amdgcn_s_setprio(0); } while (0)

#define STGA32(buf, kadd) do { \
  gload16(xbp + aof0 + (kadd), &sA[buf][0][t8]); \
  gload16(xbp + aof1 + (kadd), &sA[buf][1][t8]); } while (0)
#define STGB32(buf, kadd) do { \
  gload16(wbp + bof0 + (kadd), &sB[buf][0][t8]); \
  gload16(wbp + bof1 + (kadd), &sB[buf][1][t8]); } while (0)

// One K-tile. CUR/NXT/STGBUF compile-time; BC holds B0-31(cur), BO scratch.
#define TILE32(CUR, NXT, STGBUF, BC, BO, DOSTG, KS, DOVM, VMN, DONEXT) do { \
  /*Ph0*/ PSYNC; RDB2(BO, CUR, 1); if (DOSTG) STGA32(STGBUF, KS); MMH(aX, BC, 0, 0); \
  /*Ph1*/ PSYNC; RDA4(aY, CUR, 1); MMH(aX, BO, 0, 1); if (DOVM) VM(VMN); \
  /*Ph2*/ PSYNC; if (DONEXT) RDA4(aX, NXT, 0); if (DOSTG) STGB32(STGBUF, KS); MMH(aY, BO, 1, 1); \
  /*Ph3*/ PSYNC; if (DONEXT) RDB2(BO, NXT, 0); MMH(aY, BC, 1, 0); } while (0)

__global__ __launch_bounds__(512, 2)
void gemm256(const unsigned short* __restrict__ xbp, const unsigned short* __restrict__ wbp,
             const float* __restrict__ bias, float* __restrict__ out) {
  __shared__ unsigned short sA[4][2][4096];   // 64 KB
  __shared__ unsigned short sB[4][2][4096];   // 64 KB

  // XCD-aware bijective swizzle: grid 512 = 32(M) x 16(N)
  const int bid = blockIdx.x;
  const int swz = (bid & 7) * 64 + (bid >> 3);
  const int bm = swz >> 4, bn = swz & 15;

  const int t = threadIdx.x;
  const int lane = t & 63;
  const int wid = t >> 6;
  const int wm = wid >> 2, wn = wid & 3;
  const int wnh = wn >> 1, wnq = wn & 1;
  const int fr = lane & 15;
  const int kh = lane >> 4;                       // k-group 0..3
  const int koo = 8 * (kh ^ ((fr >> 1) & 3));     // sigma swizzle, lane-invariant

  const int t8 = t * 8;
  const int rl = t >> 2;
  const int cs = 8 * ((t & 3) ^ ((rl >> 1) & 3)); // inverse-swizzled src col
  unsigned int aof0 = (unsigned int)((bm * 256 + 0 * 128 + rl) * KDIM + cs);
  unsigned int aof1 = (unsigned int)((bm * 256 + 1 * 128 + rl) * KDIM + cs);
  unsigned int bof0 = (unsigned int)((bn * 256 + 0 * 128 + rl) * KDIM + cs);
  unsigned int bof1 = (unsigned int)((bn * 256 + 1 * 128 + rl) * KDIM + cs);

  f32x4 acc[8][4];
#pragma unroll
  for (int i = 0; i < 8; i++)
#pragma unroll
    for (int j = 0; j < 4; j++) acc[i][j] = {0.f, 0.f, 0.f, 0.f};

  bf16x8 aX[4], aY[4], b0[2], b1[2];

  // prologue: stage tiles 0,1,2 (12 loads, FIFO A0,B0,A1,B1,A2,B2)
  STGA32(0, 0);  STGB32(0, 0);
  STGA32(1, 32); STGB32(1, 32);
  STGA32(2, 64); STGB32(2, 64);
  VM(8); PSYNC;                    // tile0 confirmed (8 left)
  RDA4(aX, 0, 0); RDB2(b0, 0, 0);  // pre-read tile0 Ph0 operands

  // tiles 0..123 in unroll-4 groups; roles: even tile BC=b0, odd BC=b1
  for (int g = 0; g < 31; ++g) {
    TILE32(0, 1, 3, b0, b1, true, 96,  true, 6, true);
    TILE32(1, 2, 0, b1, b0, true, 128, true, 6, true);
    TILE32(2, 3, 1, b0, b1, true, 160, true, 6, true);
    TILE32(3, 0, 2, b1, b0, true, 192, true, 6, true);
    aof0 += 128; aof1 += 128; bof0 += 128; bof1 += 128;
  }
  // final group: tiles 124..127
  TILE32(0, 1, 3, b0, b1, true, 96, true, 6, true);    // 124: stages 127
  TILE32(1, 2, 0, b1, b0, false, 0, true, 4, true);    // 125
  TILE32(2, 3, 0, b0, b1, false, 0, true, 0, true);    // 126
  TILE32(3, 0, 0, b1, b0, false, 0, false, 0, false);  // 127 drain

  // epilogue: C/D layout col = lane&15, row = (lane>>4)*4 + q
#pragma unroll
  for (int nn = 0; nn < 4; ++nn) {
    const int col = bn * 256 + wn * 64 + nn * 16 + (lane & 15);
    const float bv = bias[col];
#pragma unroll
    for (int m = 0; m < 8; ++m) {
      const int row0 = bm * 256 + wm * 128 + m * 16 + (lane >> 4) * 4;
#pragma unroll
      for (int q = 0; q < 4; ++q)
        out[(size_t)(row0 + q) * NDIM + col] = acc[m][nn][q] + bv;
    }
  }
}

// ===== fallback 128^2 GEMM (round-3 verified) for small-ws paths =====
template <bool A_BF16, bool B_BF16>
__global__ __launch_bounds__(256)
void gemm_bt(const void* __restrict__ Av, const void* __restrict__ Bv,
             const float* __restrict__ bias, float* __restrict__ out,
             const float* __restrict__ scal) {
  __shared__ unsigned short sAt[2][128 * 32];
  __shared__ unsigned short sBt[2][128 * 32];
  float lower = 0.f, upper = 0.f, scale = 0.f;
  if constexpr (!B_BF16) { lower = scal[1]; upper = scal[2]; scale = scal[3]; }
  const unsigned short* Ab = (const unsigned short*)Av;
  const float* Af = (const float*)Av;
  const unsigned short* Bb = (const unsigned short*)Bv;
  const float* Bf = (const float*)Bv;
  int bid = blockIdx.x;
  int swz = (bid & 7) * 256 + (bid >> 3);
  int bm = swz >> 5, bn = swz & 31;
  const int t = threadIdx.x, lane = t & 63, wid = t >> 6;
  const int wm = wid >> 1, wn = wid & 1;
  const int e0 = t * 8, e1 = e0 + 2048;
  const size_t aOff0 = (size_t)(bm * 128 + (e0 >> 5)) * KDIM + (e0 & 31);
  const size_t aOff1 = (size_t)(bm * 128 + (e1 >> 5)) * KDIM + (e1 & 31);
  const size_t bOff0 = (size_t)(bn * 128 + (e0 >> 5)) * KDIM + (e0 & 31);
  const size_t bOff1 = (size_t)(bn * 128 + (e1 >> 5)) * KDIM + (e1 & 31);
  f32x4 acc[4][4];
#pragma unroll
  for (int i = 0; i < 4; i++)
#pragma unroll
    for (int j = 0; j < 4; j++) acc[i][j] = {0.f, 0.f, 0.f, 0.f};
  auto stage = [&](int buf, int k0) {
    if constexpr (A_BF16) {
      gload16(Ab + aOff0 + k0, &sAt[buf][e0]);
      gload16(Ab + aOff1 + k0, &sAt[buf][e1]);
    } else {
      pack8(Af + aOff0 + k0, &sAt[buf][e0], false, 0.f, 0.f, 0.f);
      pack8(Af + aOff1 + k0, &sAt[buf][e1], false, 0.f, 0.f, 0.f);
    }
    if constexpr (B_BF16) {
      gload16(Bb + bOff0 + k0, &sBt[buf][e0]);
      gload16(Bb + bOff1 + k0, &sBt[buf][e1]);
    } else {
      pack8(Bf + bOff0 + k0, &sBt[buf][e0], true, lower, upper, scale);
      pack8(Bf + bOff1 + k0, &sBt[buf][e1], true, lower, upper, scale);
    }
  };
  stage(0, 0);
  const int NT = KDIM / 32;
  const int ko = (lane >> 4) * 8, fr = lane & 15;
  for (int tt = 0; tt < NT; ++tt) {
    int cur = tt & 1;
    __syncthreads();
    if (tt + 1 < NT) stage(cur ^ 1, (tt + 1) * 32);
    bf16x8 a[4], b[4];
#pragma unroll
    for (int i = 0; i < 4; i++) {
      a[i] = *(const bf16x8*)&sAt[cur][(wm * 64 + i * 16 + fr) * 32 + ko];
      b[i] = *(const bf16x8*)&sBt[cur][(wn * 64 + i * 16 + fr) * 32 + ko];
    }
#pragma unroll
    for (int i = 0; i < 4; i++)
#pragma unroll
      for (int j = 0; j < 4; j++)
        acc[i][j] = __builtin_amdgcn_mfma_f32_16x16x32_bf16(a[i], b[j], acc[i][j], 0, 0, 0);
  }
  const int colbase = bn * 128 + wn * 64 + (lane & 15);
  const int rowbase = bm * 128 + wm * 64 + (lane >> 4) * 4;
#pragma unroll
  for (int j = 0; j < 4; j++) {
    int col = colbase + j * 16;
    float bv = bias[col];
#pragma unroll
    for (int i = 0; i < 4; i++) {
      int row0 = rowbase + i * 16;
#pragma unroll
      for (int q = 0; q < 4; q++)
        out[(size_t)(row0 + q) * NDIM + col] = acc[i][j][q] + bv;
    }
  }
}

extern "C" void kernel_launch(void* const* d_in, const int* in_sizes, int n_in,
                              void* d_out, int out_size, void* d_ws, size_t ws_size,
                              hipStream_t stream) {
  const float* x = (const float*)d_in[0];
  const float* w = (const float*)d_in[1];
  const float* bias = (const float*)d_in[2];
  float* out = (float*)d_out;
  char* ws = (char*)d_ws;

  const size_t xb_b = (size_t)XELEMS * 2;   // 64 MB
  const size_t wb_b = (size_t)WELEMS * 2;   // 32 MB
  const size_t c_b = 4 * 4096 * sizeof(float);
  const bool full = ws_size >= xb_b + wb_b + c_b + 64;
  const bool wonly = !full && ws_size >= wb_b + c_b + 64;

  unsigned short *xb = nullptr, *wb = nullptr;
  float *C1, *scal;
  if (full) {
    xb = (unsigned short*)ws;
    wb = (unsigned short*)(ws + xb_b);
    C1 = (float*)(ws + xb_b + wb_b);
  } else if (wonly) {
    wb = (unsigned short*)ws;
    C1 = (float*)(ws + wb_b);
  } else {
    C1 = (float*)ws;
  }
  float* C2 = C1 + 4096;
  float* C3 = C2 + 4096;
  float* C4 = C3 + 4096;
  scal = C4 + 4096;

  if (full) {
    np_stage1<0><<<dim3(4096), dim3(256), 0, stream>>>(w, C1, nullptr, scal);
    k2_var_convx<<<dim3(6144), dim3(256), 0, stream>>>(w, x, C1, C2, xb);
    k3_keep_convx<<<dim3(6144), dim3(256), 0, stream>>>(w, x, C1, C2, C3, C4, xb);
    k4_convw<<<dim3(2048), dim3(256), 0, stream>>>(w, C1, C2, C3, C4, wb);
    gemm256<<<dim3(512), dim3(512), 0, stream>>>(xb, wb, bias, out);
  } else {
    np_stage1<0><<<dim3(4096), dim3(256), 0, stream>>>(w, C1, nullptr, scal);
    np_stage2<0><<<dim3(1), dim3(256), 0, stream>>>(C1, nullptr, scal);
    np_stage1<1><<<dim3(4096), dim3(256), 0, stream>>>(w, C2, nullptr, scal);
    np_stage2<1><<<dim3(1), dim3(256), 0, stream>>>(C2, nullptr, scal);
    np_stage1<2><<<dim3(4096), dim3(256), 0, stream>>>(w, C3, C4, scal);
    np_stage2<2><<<dim3(1), dim3(256), 0, stream>>>(C3, C4, scal);
    if (wonly) {
      convert_w<<<dim3(2048), dim3(256), 0, stream>>>(w, wb, scal);
      gemm_bt<false, true><<<dim3(2048), dim3(256), 0, stream>>>(x, wb, bias, out, scal);
    } else {
      gemm_bt<false, false><<<dim3(2048), dim3(256), 0, stream>>>(x, w, bias, out, scal);
    }
  }
}